// Round 10
// baseline (97.123 us; speedup 1.0000x reference)
//
#include <hip/hip_runtime.h>
#include <stdint.h>

typedef float f32x16 __attribute__((ext_vector_type(16)));
typedef short bf16x8 __attribute__((ext_vector_type(8)));
typedef uint32_t u32;
typedef uint32_t u32x4 __attribute__((ext_vector_type(4)));

#define SIZE 784
#define NLBL 10
#define LABEL_SITE 392
#define BATCH 128
#define NPAIR 392
// table: per pair 4 terms x 2 t x 2 prec x 64 lanes x 4 u32 = 4096 u32
#define TBL_U32 ((size_t)NPAIR * 4096)

#if defined(__has_builtin)
#if __has_builtin(__builtin_amdgcn_permlane32_swap)
#define HAVE_PLSWAP 1
#endif
#endif
#ifndef HAVE_PLSWAP
#define HAVE_PLSWAP 0
#endif

// ---------- helpers ----------

__device__ inline int site_of(int ci) {
  int s = LABEL_SITE + ci;
  if (s >= SIZE) s -= SIZE;
  return s;
}

__device__ inline u32 cvt_pk(float a, float b) {
  u32 r;
  asm("v_cvt_pk_bf16_f32 %0, %1, %2" : "=v"(r) : "v"(a), "v"(b));
  return r;
}
__device__ inline float lo16f(u32 h) { return __uint_as_float(h << 16); }
__device__ inline float hi16f(u32 h) { return __uint_as_float(h & 0xffff0000u); }

// Split 8 fp32 (j-order) into packed bf16 hi/lo fragments using RNE.
__device__ inline void split_pack(const float s[8], u32 hi[4], u32 lo[4]) {
#pragma unroll
  for (int p = 0; p < 4; ++p) {
    u32 h = cvt_pk(s[2 * p], s[2 * p + 1]);
    hi[p] = h;
    lo[p] = cvt_pk(s[2 * p] - lo16f(h), s[2 * p + 1] - hi16f(h));
  }
}

__device__ inline f32x16 mfma_bb(const u32 (&a)[4], const u32 (&b)[4], f32x16 c) {
  union U { u32 u[4]; bf16x8 v; };
  U A, B;
#pragma unroll
  for (int i = 0; i < 4; ++i) { A.u[i] = a[i]; B.u[i] = b[i]; }
  return __builtin_amdgcn_mfma_f32_32x32x16_bf16(A.v, B.v, c, 0, 0, 0);
}
__device__ inline f32x16 mfma_v4(u32x4 a, const u32 (&b)[4], f32x16 c) {
  union UA { u32x4 u; bf16x8 v; } A; A.u = a;
  union UB { u32 u[4]; bf16x8 v; } B;
#pragma unroll
  for (int i = 0; i < 4; ++i) B.u[i] = b[i];
  return __builtin_amdgcn_mfma_f32_32x32x16_bf16(A.v, B.v, c, 0, 0, 0);
}

// Identity matrix in C/D fragment layout:
// row = (reg&3) + 8*(reg>>2) + 4*(lane>>5), col = lane&31
__device__ inline f32x16 ident_acc(int lane) {
  const int gam = lane & 31, hib = lane >> 5;
  f32x16 a;
#pragma unroll
  for (int reg = 0; reg < 16; ++reg) {
    int rho = (reg & 3) + 8 * (reg >> 2) + 4 * hib;
    a[reg] = (rho == gam) ? 1.0f : 0.0f;
  }
  return a;
}

// Probe v_permlane32_swap_b32 semantics (wave-uniform, deterministic).
__device__ inline int probe_mode(int lane) {
#if HAVE_PLSWAP
  u32 a = (u32)lane, b = (u32)(64 + lane);
  auto r = __builtin_amdgcn_permlane32_swap(a, b, false, false);
  u32 eLo = (u32)(lane + (lane & 32));
  u32 eHi = (u32)(lane + 32 + (lane & 32));
  if (__all(r[0] == eLo) && __all(r[1] == eHi)) return 1;
  if (__all(r[0] == eHi) && __all(r[1] == eLo)) return 2;
#endif
  return 0;
}

// Build B-operand hi/lo frags for k-half t from acc (C/D layout), in-register.
template <int MODE>
__device__ inline void build_b(const f32x16& acc, int hib, int t,
                               u32 (&Bh)[4], u32 (&Bl)[4]) {
  float slot[8];
#pragma unroll
  for (int j = 0; j < 4; ++j) {
    const int q1 = 8 * t + j, q2 = q1 + 4;
#if HAVE_PLSWAP
    if (MODE != 0) {
      u32 au = __float_as_uint(acc[q1]), bu = __float_as_uint(acc[q2]);
      auto r = __builtin_amdgcn_permlane32_swap(au, bu, false, false);
      slot[j]     = __uint_as_float(MODE == 1 ? r[0] : r[1]);
      slot[j + 4] = __uint_as_float(MODE == 1 ? r[1] : r[0]);
    } else
#endif
    {
      float z = hib ? acc[q1] : acc[q2];
      float wv = __shfl_xor(z, 32, 64);
      slot[j]     = hib ? wv : acc[q1];
      slot[j + 4] = hib ? acc[q2] : wv;
    }
  }
  split_pack(slot, Bh, Bl);
}

// One generic chain step X <- A*X with A given as hi/lo frags (phase 2).
template <int MODE>
__device__ inline f32x16 chain_step(const u32 (&Ah)[2][4], const u32 (&Al)[2][4],
                                    f32x16 acc, int hib) {
  f32x16 r;
#pragma unroll
  for (int q = 0; q < 16; ++q) r[q] = 0.0f;
#pragma unroll
  for (int t = 0; t < 2; ++t) {
    u32 Bh[4], Bl[4];
    build_b<MODE>(acc, hib, t, Bh, Bl);
    r = mfma_bb(Al[t], Bh, r);
    r = mfma_bb(Ah[t], Bl, r);
    r = mfma_bb(Ah[t], Bh, r);
  }
  return r;
}

// Store acc (C/D layout) row-major: Y[rho][gam] -> dst[rho*32+gam]. Coalesced.
__device__ inline void store_cd(float* dst, f32x16 acc, int lane) {
  const int gam = lane & 31, hib = lane >> 5;
#pragma unroll
  for (int reg = 0; reg < 16; ++reg) {
    int rho = (reg & 3) + 8 * (reg >> 2) + 4 * hib;
    dst[rho * 32 + gam] = acc[reg];
  }
}

// Load A-operand hi/lo frags of a row-major 32x32 matrix (global).
__device__ inline void load_afrag_rm(const float* src, int lane,
                                     u32 (&Ah)[2][4], u32 (&Al)[2][4]) {
  const int row = lane & 31, hb8 = (lane >> 5) * 8;
#pragma unroll
  for (int h = 0; h < 2; ++h) {
    const float* p = src + row * 32 + h * 16 + hb8;
    float4 q0 = *(const float4*)p;
    float4 q1 = *(const float4*)(p + 4);
    float v[8] = {q0.x, q0.y, q0.z, q0.w, q1.x, q1.y, q1.z, q1.w};
    split_pack(v, Ah[h], Al[h]);
  }
}

// 6-MFMA product chain: r = T(hi+lo over t) * B(hi+lo), C-init = z (hoisted zero)
__device__ inline f32x16 chain6(u32x4 Th0, u32x4 Tl0, u32x4 Th1, u32x4 Tl1,
                                const u32 (&B0h)[4], const u32 (&B0l)[4],
                                const u32 (&B1h)[4], const u32 (&B1l)[4],
                                const f32x16& z) {
  f32x16 r = mfma_v4(Tl0, B0h, z);
  r = mfma_v4(Th0, B0l, r);
  r = mfma_v4(Th0, B0h, r);
  r = mfma_v4(Tl1, B1h, r);
  r = mfma_v4(Th1, B1l, r);
  r = mfma_v4(Th1, B1h, r);
  return r;
}

// ---------- phase 0: pair-product table ----------
// Block m = pair p: sites sA = site(2p) (applied first), sB = site(2p+1).
// A-form: C(r,k) = core[s*2048 + k*64 + r], D(r,k) = core[...+32+r] - C(r,k).
// A_P = A(sB)*A(sA) = CBCA + x0*CBDA + x1*DBCA + x0x1*DBDA.
// Wave w computes term w in exact fp32, splits hi/lo into A-frag layout:
// table u32 idx = p*4096 + (w*4 + t*2 + prec)*256 + lane*4.
__global__ __launch_bounds__(256) void mps_precomp_pairs(const float* __restrict__ core,
                                                         u32* __restrict__ table) {
  __shared__ float CA[32 * 33], DA[32 * 33], CB[32 * 33], DB[32 * 33];
  const int tid = threadIdx.x;
  const int w = tid >> 6, lane = tid & 63;
  const int p = blockIdx.x;
  const int sA = site_of(2 * p), sB = site_of(2 * p + 1);
  for (int f = tid; f < 2048; f += 256) {
    int r = f & 31, e = (f >> 5) & 1, k = f >> 6;
    float vA = core[(size_t)sA * 2048 + f];
    float vB = core[(size_t)sB * 2048 + f];
    if (e == 0) { CA[r * 33 + k] = vA; CB[r * 33 + k] = vB; }
    else        { DA[r * 33 + k] = vA; DB[r * 33 + k] = vB; }
  }
  __syncthreads();
  for (int f = tid; f < 1024; f += 256) {
    int r = f & 31, k = f >> 5;
    DA[r * 33 + k] -= CA[r * 33 + k];
    DB[r * 33 + k] -= CB[r * 33 + k];
  }
  __syncthreads();
  const float* Lm = (w < 2) ? CB : DB;
  const float* Rm = (w & 1) ? DA : CA;
  const int r = lane & 31, hib = lane >> 5;
  float Lr[32];
#pragma unroll
  for (int j = 0; j < 32; ++j) Lr[j] = Lm[r * 33 + j];
#pragma unroll
  for (int t = 0; t < 2; ++t) {
    float o[8];
#pragma unroll
    for (int jj = 0; jj < 8; ++jj) {
      const int k = 16 * t + 8 * hib + jj;
      float s = 0.0f;
#pragma unroll
      for (int j = 0; j < 32; ++j) s = fmaf(Lr[j], Rm[j * 33 + k], s);
      o[jj] = s;
    }
    u32 hi[4], lo[4];
    split_pack(o, hi, lo);
    const size_t base = (size_t)p * 4096 + (size_t)(w * 4 + t * 2) * 256 + lane * 4;
    *(u32x4*)(table + base) = *(u32x4*)hi;
    *(u32x4*)(table + base + 256) = *(u32x4*)lo;
  }
}

// ---------- phase 1: pair-fused chain ----------
template <int MODE>
__device__ void phase1_body(const float* __restrict__ input,
                            const u32* __restrict__ table,
                            float* __restrict__ wsA, int nseg, int pairs,
                            int lane, int bi, int g) {
  const int hib = lane >> 5;
  f32x16 acc = ident_acc(lane);
  f32x16 z16;
#pragma unroll
  for (int q = 0; q < 16; ++q) z16[q] = 0.0f;
  const int ci0 = g * 2 * pairs;
  for (int i = 0; i < pairs; ++i) {
    const int ci = ci0 + 2 * i;
    const float x0 = input[(size_t)bi * SIZE + site_of(ci)];
    const float x1 = input[(size_t)bi * SIZE + site_of(ci + 1)];
    const u32* tb = table + (size_t)(g * pairs + i) * 4096 + lane * 4;
    u32x4 T[16];
#pragma unroll
    for (int q = 0; q < 16; ++q) T[q] = *(const u32x4*)(tb + q * 256);
    u32 B0h[4], B0l[4], B1h[4], B1l[4];
    build_b<MODE>(acc, hib, 0, B0h, B0l);
    build_b<MODE>(acc, hib, 1, B1h, B1l);
    // T[q]: q = term*4 + t*2 + prec (prec0=hi, prec1=lo)
    f32x16 rcc = chain6(T[0],  T[1],  T[2],  T[3],  B0h, B0l, B1h, B1l, z16);
    f32x16 rcd = chain6(T[4],  T[5],  T[6],  T[7],  B0h, B0l, B1h, B1l, z16);
    f32x16 rdc = chain6(T[8],  T[9],  T[10], T[11], B0h, B0l, B1h, B1l, z16);
    f32x16 rdd = chain6(T[12], T[13], T[14], T[15], B0h, B0l, B1h, B1l, z16);
#pragma unroll
    for (int q = 0; q < 16; ++q)
      acc[q] = fmaf(x1, fmaf(x0, rdd[q], rdc[q]), fmaf(x0, rcd[q], rcc[q]));
  }
  store_cd(wsA + ((size_t)bi * nseg + g) * 1024, acc, lane);
}

__global__ __launch_bounds__(256) void mps_phase1(
    const float* __restrict__ input, const u32* __restrict__ table,
    float* __restrict__ wsA, int nseg, int pairs) {
  const int tid = threadIdx.x;
  const int w = tid >> 6, lane = tid & 63;
  const int g = blockIdx.x % nseg, c = blockIdx.x / nseg;
  const int bi = c * 4 + w;
  const int mode = probe_mode(lane);
  if (mode == 1)      phase1_body<1>(input, table, wsA, nseg, pairs, lane, bi, g);
  else if (mode == 2) phase1_body<2>(input, table, wsA, nseg, pairs, lane, bi, g);
  else                phase1_body<0>(input, table, wsA, nseg, pairs, lane, bi, g);
}

// ---------- phase 2a: combine 7 consecutive segment products ----------
template <int MODE>
__device__ void phase2a_body(const float* __restrict__ wsA, float* __restrict__ wsB,
                             int nseg, int lane, int bi, int gg) {
  f32x16 acc = ident_acc(lane);
  for (int g = gg * 7; g < gg * 7 + 7; ++g) {
    u32 Ah[2][4], Al[2][4];
    load_afrag_rm(wsA + ((size_t)bi * nseg + g) * 1024, lane, Ah, Al);
    acc = chain_step<MODE>(Ah, Al, acc, lane >> 5);
  }
  const int ngroups = nseg / 7;
  store_cd(wsB + ((size_t)bi * ngroups + gg) * 1024, acc, lane);
}

__global__ __launch_bounds__(256) void mps_phase2a(const float* __restrict__ wsA,
                                                   float* __restrict__ wsB,
                                                   int nseg) {
  const int tid = threadIdx.x;
  const int w = tid >> 6, lane = tid & 63;
  const int wid = blockIdx.x * 4 + w;
  const int bi = wid & 127, gg = wid >> 7;
  const int mode = probe_mode(lane);
  if (mode == 1)      phase2a_body<1>(wsA, wsB, nseg, lane, bi, gg);
  else if (mode == 2) phase2a_body<2>(wsA, wsB, nseg, lane, bi, gg);
  else                phase2a_body<0>(wsA, wsB, nseg, lane, bi, gg);
}

// ---------- phase 2b: final combine (ngroups) + trace epilogue ----------
template <int MODE>
__device__ void phase2b_body(const float* __restrict__ wsB,
                             const float* __restrict__ label,
                             float* __restrict__ out, int ngroups,
                             int lane, int bi) {
  const int gam = lane & 31, hib = lane >> 5;
  f32x16 acc = ident_acc(lane);
  for (int gg = 0; gg < ngroups; ++gg) {
    u32 Ah[2][4], Al[2][4];
    load_afrag_rm(wsB + ((size_t)bi * ngroups + gg) * 1024, lane, Ah, Al);
    acc = chain_step<MODE>(Ah, Al, acc, hib);
  }
  float part[NLBL];
#pragma unroll
  for (int l = 0; l < NLBL; ++l) part[l] = 0.0f;
#pragma unroll
  for (int reg = 0; reg < 16; ++reg) {
    const int rho = (reg & 3) + 8 * (reg >> 2) + 4 * hib;
    const float wv = acc[reg];
    const float* tp = label + rho * (NLBL * 32) + gam;
#pragma unroll
    for (int l = 0; l < NLBL; ++l) part[l] = fmaf(tp[l * 32], wv, part[l]);
  }
#pragma unroll
  for (int l = 0; l < NLBL; ++l) {
#pragma unroll
    for (int mask = 32; mask >= 1; mask >>= 1)
      part[l] += __shfl_xor(part[l], mask, 64);
  }
  if (lane == 0) {
#pragma unroll
    for (int l = 0; l < NLBL; ++l) out[bi * NLBL + l] = part[l];
  }
}

__global__ __launch_bounds__(256) void mps_phase2b(const float* __restrict__ wsB,
                                                   const float* __restrict__ label,
                                                   float* __restrict__ out,
                                                   int ngroups) {
  const int tid = threadIdx.x;
  const int w = tid >> 6, lane = tid & 63;
  const int bi = blockIdx.x * 4 + w;
  const int mode = probe_mode(lane);
  if (mode == 1)      phase2b_body<1>(wsB, label, out, ngroups, lane, bi);
  else if (mode == 2) phase2b_body<2>(wsB, label, out, ngroups, lane, bi);
  else                phase2b_body<0>(wsB, label, out, ngroups, lane, bi);
}

extern "C" void kernel_launch(void* const* d_in, const int* in_sizes, int n_in,
                              void* d_out, int out_size, void* d_ws, size_t ws_size,
                              hipStream_t stream) {
  const float* input = (const float*)d_in[0];  // [128,784]
  const float* core  = (const float*)d_in[1];  // [784,32,2,32]
  const float* label = (const float*)d_in[2];  // [32,10,32]
  float* out = (float*)d_out;                  // [128,10]

  // workspace: [pair table | wsA | wsB]
  u32* table = (u32*)d_ws;
  float* wsA = (float*)(table + TBL_U32);

  // nseg=98 (seglen 8, 4 pairs) needs 6.42 + 51.38 + 7.34 = 65,142,784 B
  const size_t need98 = (TBL_U32 + (size_t)BATCH * 98 * 1024 +
                         (size_t)BATCH * 14 * 1024) * 4;
  const int nseg = (ws_size >= need98) ? 98 : 56;  // 98: 4 pairs; 56: 7 pairs
  const int pairs = (SIZE / nseg) / 2;
  const int ngroups = nseg / 7;
  float* wsB = wsA + (size_t)BATCH * nseg * 1024;

  mps_precomp_pairs<<<dim3(NPAIR), dim3(256), 0, stream>>>(core, table);
  mps_phase1<<<dim3(nseg * 32), dim3(256), 0, stream>>>(input, table, wsA, nseg, pairs);
  mps_phase2a<<<dim3(32 * ngroups), dim3(256), 0, stream>>>(wsA, wsB, nseg);
  mps_phase2b<<<dim3(32), dim3(256), 0, stream>>>(wsB, label, out, ngroups);
}

// Round 11
// 70.087 us; speedup vs baseline: 1.3857x; 1.3857x over previous
//
#include <hip/hip_runtime.h>
#include <stdint.h>

typedef float f32x16 __attribute__((ext_vector_type(16)));
typedef short bf16x8 __attribute__((ext_vector_type(8)));
typedef uint32_t u32;
typedef uint32_t u32x4 __attribute__((ext_vector_type(4)));

#define SIZE 784
#define NLBL 10
#define LABEL_SITE 392
#define BATCH 128
#define PRE_ELEMS (SIZE * 2 * 64 * 4)   // u32 per A-frag table array
#define MAXSEG 112
#define LSTR 33
#define LSLOT (LSTR * 32)

#if defined(__has_builtin)
#if __has_builtin(__builtin_amdgcn_permlane32_swap)
#define HAVE_PLSWAP 1
#endif
#endif
#ifndef HAVE_PLSWAP
#define HAVE_PLSWAP 0
#endif

// ---------- helpers ----------

__device__ inline int site_of(int ci) {
  int s = LABEL_SITE + ci;
  if (s >= SIZE) s -= SIZE;
  return s;
}

__device__ inline u32 cvt_pk(float a, float b) {
  u32 r;
  asm("v_cvt_pk_bf16_f32 %0, %1, %2" : "=v"(r) : "v"(a), "v"(b));
  return r;
}
__device__ inline float lo16f(u32 h) { return __uint_as_float(h << 16); }
__device__ inline float hi16f(u32 h) { return __uint_as_float(h & 0xffff0000u); }

// Split 8 fp32 (j-order) into packed bf16 hi/lo fragments using RNE.
__device__ inline void split_pack(const float s[8], u32 hi[4], u32 lo[4]) {
#pragma unroll
  for (int p = 0; p < 4; ++p) {
    u32 h = cvt_pk(s[2 * p], s[2 * p + 1]);
    hi[p] = h;
    lo[p] = cvt_pk(s[2 * p] - lo16f(h), s[2 * p + 1] - hi16f(h));
  }
}

__device__ inline f32x16 mfma_bb(const u32 (&a)[4], const u32 (&b)[4], f32x16 c) {
  union U { u32 u[4]; bf16x8 v; };
  U A, B;
#pragma unroll
  for (int i = 0; i < 4; ++i) { A.u[i] = a[i]; B.u[i] = b[i]; }
  return __builtin_amdgcn_mfma_f32_32x32x16_bf16(A.v, B.v, c, 0, 0, 0);
}
__device__ inline f32x16 mfma_v4(u32x4 a, const u32 (&b)[4], f32x16 c) {
  union UA { u32x4 u; bf16x8 v; } A; A.u = a;
  union UB { u32 u[4]; bf16x8 v; } B;
#pragma unroll
  for (int i = 0; i < 4; ++i) B.u[i] = b[i];
  return __builtin_amdgcn_mfma_f32_32x32x16_bf16(A.v, B.v, c, 0, 0, 0);
}

// Probe v_permlane32_swap_b32 semantics (wave-uniform, deterministic).
__device__ inline int probe_mode(int lane) {
#if HAVE_PLSWAP
  u32 a = (u32)lane, b = (u32)(64 + lane);
  auto r = __builtin_amdgcn_permlane32_swap(a, b, false, false);
  u32 eLo = (u32)(lane + (lane & 32));
  u32 eHi = (u32)(lane + 32 + (lane & 32));
  if (__all(r[0] == eLo) && __all(r[1] == eHi)) return 1;
  if (__all(r[0] == eHi) && __all(r[1] == eLo)) return 2;
#endif
  return 0;
}

// Build B-operand hi/lo frags for k-half t from acc (C/D layout), in-register.
template <int MODE>
__device__ inline void build_b(const f32x16& acc, int hib, int t,
                               u32 (&Bh)[4], u32 (&Bl)[4]) {
  float slot[8];
#pragma unroll
  for (int j = 0; j < 4; ++j) {
    const int q1 = 8 * t + j, q2 = q1 + 4;
#if HAVE_PLSWAP
    if (MODE != 0) {
      u32 au = __float_as_uint(acc[q1]), bu = __float_as_uint(acc[q2]);
      auto r = __builtin_amdgcn_permlane32_swap(au, bu, false, false);
      slot[j]     = __uint_as_float(MODE == 1 ? r[0] : r[1]);
      slot[j + 4] = __uint_as_float(MODE == 1 ? r[1] : r[0]);
    } else
#endif
    {
      float z = hib ? acc[q1] : acc[q2];
      float wv = __shfl_xor(z, 32, 64);
      slot[j]     = hib ? wv : acc[q1];
      slot[j + 4] = hib ? acc[q2] : wv;
    }
  }
  split_pack(slot, Bh, Bl);
}

// One generic chain step X <- A*X with A given as hi/lo frags.
template <int MODE>
__device__ inline f32x16 chain_step(const u32 (&Ah)[2][4], const u32 (&Al)[2][4],
                                    f32x16 acc, int hib) {
  f32x16 r;
#pragma unroll
  for (int q = 0; q < 16; ++q) r[q] = 0.0f;
#pragma unroll
  for (int t = 0; t < 2; ++t) {
    u32 Bh[4], Bl[4];
    build_b<MODE>(acc, hib, t, Bh, Bl);
    r = mfma_bb(Al[t], Bh, r);
    r = mfma_bb(Ah[t], Bl, r);
    r = mfma_bb(Ah[t], Bh, r);
  }
  return r;
}

// Store acc (C/D layout) row-major: Y[rho][gam] -> dst[rho*32+gam]. Coalesced.
__device__ inline void store_cd(float* dst, f32x16 acc, int lane) {
  const int gam = lane & 31, hib = lane >> 5;
#pragma unroll
  for (int reg = 0; reg < 16; ++reg) {
    int rho = (reg & 3) + 8 * (reg >> 2) + 4 * hib;
    dst[rho * 32 + gam] = acc[reg];
  }
}

// Load a row-major 32x32 matrix straight into C/D accumulator layout.
__device__ inline f32x16 load_cd_rm(const float* src, int lane) {
  const int gam = lane & 31, hib = lane >> 5;
  f32x16 a;
#pragma unroll
  for (int reg = 0; reg < 16; ++reg) {
    int rho = (reg & 3) + 8 * (reg >> 2) + 4 * hib;
    a[reg] = src[rho * 32 + gam];
  }
  return a;
}

// Raw 16-float A-slice load (row-major 32x32) + split (A-frag layout).
__device__ inline void load_raw(float4 (&q)[4], const float* src, int lane) {
  const int row = lane & 31, hb8 = (lane >> 5) * 8;
  const float* p = src + row * 32 + hb8;
  q[0] = *(const float4*)(p);
  q[1] = *(const float4*)(p + 4);
  q[2] = *(const float4*)(p + 16);
  q[3] = *(const float4*)(p + 20);
}
__device__ inline void split_raw(const float4 (&q)[4],
                                 u32 (&Ah)[2][4], u32 (&Al)[2][4]) {
#pragma unroll
  for (int h = 0; h < 2; ++h) {
    float v[8] = {q[2 * h].x, q[2 * h].y, q[2 * h].z, q[2 * h].w,
                  q[2 * h + 1].x, q[2 * h + 1].y, q[2 * h + 1].z, q[2 * h + 1].w};
    split_pack(v, Ah[h], Al[h]);
  }
}

// Load A-operand hi/lo frags of a row-major 32x32 matrix (global).
__device__ inline void load_afrag_rm(const float* src, int lane,
                                     u32 (&Ah)[2][4], u32 (&Al)[2][4]) {
  float4 q[4];
  load_raw(q, src, lane);
  split_raw(q, Ah, Al);
}

// LDS variants with padded stride LSTR (bank-conflict-free).
__device__ inline void store_cd33(float* dst, f32x16 acc, int lane) {
  const int gam = lane & 31, hib = lane >> 5;
#pragma unroll
  for (int reg = 0; reg < 16; ++reg) {
    int rho = (reg & 3) + 8 * (reg >> 2) + 4 * hib;
    dst[rho * LSTR + gam] = acc[reg];
  }
}
__device__ inline f32x16 load_cd33(const float* src, int lane) {
  const int gam = lane & 31, hib = lane >> 5;
  f32x16 a;
#pragma unroll
  for (int reg = 0; reg < 16; ++reg) {
    int rho = (reg & 3) + 8 * (reg >> 2) + 4 * hib;
    a[reg] = src[rho * LSTR + gam];
  }
  return a;
}
__device__ inline void load_afrag_lds33(const float* src, int lane,
                                        u32 (&Ah)[2][4], u32 (&Al)[2][4]) {
  const int row = lane & 31, hb8 = (lane >> 5) * 8;
#pragma unroll
  for (int h = 0; h < 2; ++h) {
    float v[8];
#pragma unroll
    for (int j = 0; j < 8; ++j) v[j] = src[row * LSTR + h * 16 + hb8 + j];
    split_pack(v, Ah[h], Al[h]);
  }
}

// ---------- phase 0: A-frag tables + exact C/D-layout segment-start inits ----
__global__ __launch_bounds__(256) void mps_precomp(const float* __restrict__ core,
                                                   u32* __restrict__ pc0h,
                                                   u32* __restrict__ pc0l,
                                                   u32* __restrict__ pdh,
                                                   u32* __restrict__ pdl,
                                                   float* __restrict__ pcd0,
                                                   float* __restrict__ pcdd,
                                                   int seglen) {
  const int tid = threadIdx.x;
  const int w = tid >> 6, lane = tid & 63;
  const int task = blockIdx.x * 4 + w;       // 0..1567
  const int s = task >> 1, t = task & 1;
  const int r = lane & 31, hib = lane >> 5;
  const float* cs = core + (size_t)s * 2048 + r;
  u32 wc0h[4], wc0l[4], wdh[4], wdl[4];
#pragma unroll
  for (int p = 0; p < 4; ++p) {
    const int k0 = 16 * t + 8 * hib + 2 * p;
    float a0 = cs[k0 * 64],       a1 = cs[(k0 + 1) * 64];
    float b0 = cs[k0 * 64 + 32],  b1 = cs[(k0 + 1) * 64 + 32];
    float d0 = b0 - a0, d1 = b1 - a1;
    u32 h = cvt_pk(a0, a1);
    wc0h[p] = h;
    wc0l[p] = cvt_pk(a0 - lo16f(h), a1 - hi16f(h));
    u32 gg = cvt_pk(d0, d1);
    wdh[p] = gg;
    wdl[p] = cvt_pk(d0 - lo16f(gg), d1 - hi16f(gg));
  }
  const size_t base = ((size_t)task * 64 + lane) * 4;
  *(u32x4*)(pc0h + base) = *(u32x4*)wc0h;
  *(u32x4*)(pc0l + base) = *(u32x4*)wc0l;
  *(u32x4*)(pdh  + base) = *(u32x4*)wdh;
  *(u32x4*)(pdl  + base) = *(u32x4*)wdl;

  // exact fp32 C/D-layout init for segment-start sites
  const int ci = (s + LABEL_SITE) % SIZE;   // chain index of site s
  if (ci % seglen == 0) {
    const int g = ci / seglen;
    const int gam = lane & 31;
#pragma unroll
    for (int rr = 0; rr < 8; ++rr) {
      const int reg = 8 * t + rr;
      const int rho = (reg & 3) + 8 * (reg >> 2) + 4 * hib;
      float c0v = core[(size_t)s * 2048 + gam * 64 + rho];
      float c1v = core[(size_t)s * 2048 + gam * 64 + 32 + rho];
      pcd0[g * 1024 + rho * 32 + gam] = c0v;
      pcdd[g * 1024 + rho * 32 + gam] = c1v - c0v;
    }
  }
}

// ---------- phase 1: per-segment chain, exact init + register prefetch ------
struct Frags {
  u32x4 C0h[2], C0l[2], Dh[2], Dl[2];
  float x;
};

__device__ inline void load_frags(Frags& F,
                                  const u32* __restrict__ pc0h, const u32* __restrict__ pc0l,
                                  const u32* __restrict__ pdh,  const u32* __restrict__ pdl,
                                  const float* __restrict__ input, int bi, int s, int lane) {
  F.x = input[(size_t)bi * SIZE + s];
#pragma unroll
  for (int t = 0; t < 2; ++t) {
    const size_t base = ((size_t)(s * 2 + t) * 64 + lane) * 4;
    F.C0h[t] = *(const u32x4*)(pc0h + base);
    F.C0l[t] = *(const u32x4*)(pc0l + base);
    F.Dh[t]  = *(const u32x4*)(pdh + base);
    F.Dl[t]  = *(const u32x4*)(pdl + base);
  }
}

template <int MODE>
__device__ inline void do_step(f32x16& acc, const Frags& F, int hib) {
  f32x16 rc, rd;
#pragma unroll
  for (int q = 0; q < 16; ++q) { rc[q] = 0.0f; rd[q] = 0.0f; }
#pragma unroll
  for (int t = 0; t < 2; ++t) {
    u32 Bh[4], Bl[4];
    build_b<MODE>(acc, hib, t, Bh, Bl);
    rd = mfma_v4(F.Dl[t], Bh, rd);
    rd = mfma_v4(F.Dh[t], Bl, rd);
    rd = mfma_v4(F.Dh[t], Bh, rd);
    rc = mfma_v4(F.C0l[t], Bh, rc);
    rc = mfma_v4(F.C0h[t], Bl, rc);
    rc = mfma_v4(F.C0h[t], Bh, rc);
  }
#pragma unroll
  for (int q = 0; q < 16; ++q) acc[q] = fmaf(F.x, rd[q], rc[q]);
}

template <int SEGLEN, int MODE>
__device__ void phase1_body(const float* __restrict__ input,
                            const u32* __restrict__ pc0h, const u32* __restrict__ pc0l,
                            const u32* __restrict__ pdh,  const u32* __restrict__ pdl,
                            const float* __restrict__ pcd0, const float* __restrict__ pcdd,
                            float* __restrict__ wsA, int nseg,
                            int lane, int bi, int g) {
  const int hib = lane >> 5;
  const int gam = lane & 31;
  const int ci0 = g * SEGLEN;
  Frags FA, FB;
  load_frags(FA, pc0h, pc0l, pdh, pdl, input, bi, site_of(ci0 + 1), lane);
  const float x0 = input[(size_t)bi * SIZE + site_of(ci0)];
  f32x16 acc;
  {
    const float* p0 = pcd0 + g * 1024;
    const float* pd = pcdd + g * 1024;
#pragma unroll
    for (int reg = 0; reg < 16; ++reg) {
      const int rho = (reg & 3) + 8 * (reg >> 2) + 4 * hib;
      acc[reg] = fmaf(x0, pd[rho * 32 + gam], p0[rho * 32 + gam]);
    }
  }
#pragma unroll
  for (int i = 1; i < SEGLEN; ++i) {
    if (((i - 1) & 1) == 0) {
      if (i + 1 < SEGLEN)
        load_frags(FB, pc0h, pc0l, pdh, pdl, input, bi, site_of(ci0 + i + 1), lane);
      do_step<MODE>(acc, FA, hib);
    } else {
      if (i + 1 < SEGLEN)
        load_frags(FA, pc0h, pc0l, pdh, pdl, input, bi, site_of(ci0 + i + 1), lane);
      do_step<MODE>(acc, FB, hib);
    }
  }
  store_cd(wsA + ((size_t)bi * nseg + g) * 1024, acc, lane);
}

template <int SEGLEN>
__global__ __launch_bounds__(256) void mps_phase1(
    const float* __restrict__ input,
    const u32* __restrict__ pc0h, const u32* __restrict__ pc0l,
    const u32* __restrict__ pdh,  const u32* __restrict__ pdl,
    const float* __restrict__ pcd0, const float* __restrict__ pcdd,
    float* __restrict__ wsA, int nseg) {
  const int tid = threadIdx.x;
  const int w = tid >> 6, lane = tid & 63;
  const int g = blockIdx.x % nseg, c = blockIdx.x / nseg;
  const int bi = c * 4 + w;
  const int mode = probe_mode(lane);
  if (mode == 1)
    phase1_body<SEGLEN, 1>(input, pc0h, pc0l, pdh, pdl, pcd0, pcdd, wsA, nseg, lane, bi, g);
  else if (mode == 2)
    phase1_body<SEGLEN, 2>(input, pc0h, pc0l, pdh, pdl, pcd0, pcdd, wsA, nseg, lane, bi, g);
  else
    phase1_body<SEGLEN, 0>(input, pc0h, pc0l, pdh, pdl, pcd0, pcdd, wsA, nseg, lane, bi, g);
}

// ---------- phase 2a: combine GG consecutive segments (first = direct load) --
template <int MODE>
__device__ void phase2a_body(const float* __restrict__ wsA, float* __restrict__ wsB,
                             int nseg, int GG, int ngroups,
                             int lane, int bi, int gg) {
  const float* srcb = wsA + ((size_t)bi * nseg + gg * GG) * 1024;
  f32x16 acc = load_cd_rm(srcb, lane);
  float4 qa[4];
  load_raw(qa, srcb + 1024, lane);
  for (int k = 1; k < GG; ++k) {
    float4 qb[4];
    if (k + 1 < GG) load_raw(qb, srcb + (size_t)(k + 1) * 1024, lane);
    u32 Ah[2][4], Al[2][4];
    split_raw(qa, Ah, Al);
    acc = chain_step<MODE>(Ah, Al, acc, lane >> 5);
    if (k + 1 < GG) { qa[0] = qb[0]; qa[1] = qb[1]; qa[2] = qb[2]; qa[3] = qb[3]; }
  }
  store_cd(wsB + ((size_t)bi * ngroups + gg) * 1024, acc, lane);
}

__global__ __launch_bounds__(256) void mps_phase2a(const float* __restrict__ wsA,
                                                   float* __restrict__ wsB,
                                                   int nseg, int GG, int ngroups) {
  const int tid = threadIdx.x;
  const int w = tid >> 6, lane = tid & 63;
  const int wid = blockIdx.x * 4 + w;
  const int bi = wid & 127, gg = wid >> 7;
  const int mode = probe_mode(lane);
  if (mode == 1)      phase2a_body<1>(wsA, wsB, nseg, GG, ngroups, lane, bi, gg);
  else if (mode == 2) phase2a_body<2>(wsA, wsB, nseg, GG, ngroups, lane, bi, gg);
  else                phase2a_body<0>(wsA, wsB, nseg, GG, ngroups, lane, bi, gg);
}

// ---------- phase 2f: fused final combine (8-wave LDS tree) + trace ---------
template <int MODE>
__device__ void phase2f_body(const float* __restrict__ wsB,
                             const float* __restrict__ label,
                             float* __restrict__ out, int ngroups,
                             int lane, int w, int bi, float* lds) {
  f32x16 acc;
  if (ngroups == 14) {
    if (w < 6) {
      acc = load_cd_rm(wsB + ((size_t)bi * 14 + 2 * w) * 1024, lane);
      u32 Ah[2][4], Al[2][4];
      load_afrag_rm(wsB + ((size_t)bi * 14 + 2 * w + 1) * 1024, lane, Ah, Al);
      acc = chain_step<MODE>(Ah, Al, acc, lane >> 5);
    } else {
      acc = load_cd_rm(wsB + ((size_t)bi * 14 + 6 + w) * 1024, lane);  // 12, 13
    }
  } else {  // ngroups == 8
    acc = load_cd_rm(wsB + ((size_t)bi * ngroups + w) * 1024, lane);
  }
  store_cd33(lds + w * LSLOT, acc, lane);
  __syncthreads();
  f32x16 na;
#pragma unroll
  for (int lvl = 4; lvl >= 1; lvl >>= 1) {
    const bool act = (w < lvl);
    if (act) {
      f32x16 a = load_cd33(lds + (2 * w) * LSLOT, lane);
      u32 Ah[2][4], Al[2][4];
      load_afrag_lds33(lds + (2 * w + 1) * LSLOT, lane, Ah, Al);
      na = chain_step<MODE>(Ah, Al, a, lane >> 5);
    }
    __syncthreads();
    if (act) store_cd33(lds + w * LSLOT, na, lane);
    __syncthreads();
  }
  if (w == 0) {
    const int gam = lane & 31, hib = lane >> 5;
    float part[NLBL];
#pragma unroll
    for (int l = 0; l < NLBL; ++l) part[l] = 0.0f;
#pragma unroll
    for (int reg = 0; reg < 16; ++reg) {
      const int rho = (reg & 3) + 8 * (reg >> 2) + 4 * hib;
      const float wv = na[reg];
      const float* tp = label + rho * (NLBL * 32) + gam;
#pragma unroll
      for (int l = 0; l < NLBL; ++l) part[l] = fmaf(tp[l * 32], wv, part[l]);
    }
#pragma unroll
    for (int l = 0; l < NLBL; ++l) {
#pragma unroll
      for (int mask = 32; mask >= 1; mask >>= 1)
        part[l] += __shfl_xor(part[l], mask, 64);
    }
    if (lane == 0) {
#pragma unroll
      for (int l = 0; l < NLBL; ++l) out[bi * NLBL + l] = part[l];
    }
  }
}

__global__ __launch_bounds__(512) void mps_phase2f(const float* __restrict__ wsB,
                                                   const float* __restrict__ label,
                                                   float* __restrict__ out,
                                                   int ngroups) {
  __shared__ float lds[8 * LSLOT];
  const int tid = threadIdx.x;
  const int w = tid >> 6, lane = tid & 63;
  const int bi = blockIdx.x;
  const int mode = probe_mode(lane);
  if (mode == 1)      phase2f_body<1>(wsB, label, out, ngroups, lane, w, bi, lds);
  else if (mode == 2) phase2f_body<2>(wsB, label, out, ngroups, lane, w, bi, lds);
  else                phase2f_body<0>(wsB, label, out, ngroups, lane, w, bi, lds);
}

extern "C" void kernel_launch(void* const* d_in, const int* in_sizes, int n_in,
                              void* d_out, int out_size, void* d_ws, size_t ws_size,
                              hipStream_t stream) {
  const float* input = (const float*)d_in[0];  // [128,784]
  const float* core  = (const float*)d_in[1];  // [784,32,2,32]
  const float* label = (const float*)d_in[2];  // [32,10,32]
  float* out = (float*)d_out;                  // [128,10]

  // workspace: [c0h | c0l | dh | dl | pcd0 | pcdd | wsA | wsB]
  u32* pc0h = (u32*)d_ws;
  u32* pc0l = pc0h + PRE_ELEMS;
  u32* pdh  = pc0l + PRE_ELEMS;
  u32* pdl  = pdh + PRE_ELEMS;
  float* pcd0 = (float*)(pdl + PRE_ELEMS);
  float* pcdd = pcd0 + (size_t)MAXSEG * 1024;
  float* wsA  = pcdd + (size_t)MAXSEG * 1024;

  const size_t base_elems = (size_t)4 * PRE_ELEMS + (size_t)2 * MAXSEG * 1024;
  const size_t need112 = (base_elems + (size_t)BATCH * 112 * 1024 +
                          (size_t)BATCH * 14 * 1024) * 4;   // 73,400,320 B
  int nseg, seglen, GG, ngroups;
  if (ws_size >= need112) { nseg = 112; seglen = 7;  GG = 8; ngroups = 14; }
  else                    { nseg = 56;  seglen = 14; GG = 7; ngroups = 8;  }
  float* wsB = wsA + (size_t)BATCH * nseg * 1024;

  mps_precomp<<<dim3(392), dim3(256), 0, stream>>>(core, pc0h, pc0l, pdh, pdl,
                                                   pcd0, pcdd, seglen);
  if (seglen == 7)
    mps_phase1<7><<<dim3(nseg * 32), dim3(256), 0, stream>>>(
        input, pc0h, pc0l, pdh, pdl, pcd0, pcdd, wsA, nseg);
  else
    mps_phase1<14><<<dim3(nseg * 32), dim3(256), 0, stream>>>(
        input, pc0h, pc0l, pdh, pdl, pcd0, pcdd, wsA, nseg);
  mps_phase2a<<<dim3((BATCH * ngroups) / 4), dim3(256), 0, stream>>>(
      wsA, wsB, nseg, GG, ngroups);
  mps_phase2f<<<dim3(BATCH), dim3(512), 0, stream>>>(wsB, label, out, ngroups);
}